// Round 13
// baseline (100.006 us; speedup 1.0000x reference)
//
#include <hip/hip_runtime.h>

#define B_   8192
#define DIN  512
#define DOUT 512
#define NC   8

typedef float  f32x4 __attribute__((ext_vector_type(4)));
typedef short  s16x8 __attribute__((ext_vector_type(8)));
typedef unsigned short u16x4 __attribute__((ext_vector_type(4)));
typedef unsigned int   u32x4 __attribute__((ext_vector_type(4)));

__device__ __forceinline__ unsigned short f2bf(float f) {
  unsigned u = __builtin_bit_cast(unsigned, f);
  u += 0x7fffu + ((u >> 16) & 1u);          // RTNE
  return (unsigned short)(u >> 16);
}
__device__ __forceinline__ float bf2f(unsigned short h) {
  unsigned u = ((unsigned)h) << 16;
  return __builtin_bit_cast(float, u);
}
__device__ __forceinline__ unsigned cvtpk(float lo, float hi) {
  unsigned r;
  asm("v_cvt_pk_bf16_f32 %0, %1, %2" : "=v"(r) : "v"(lo), "v"(hi));
  return r;
}

// ---------- fused pack: x (f32->bf16) and w (f32 -> MFMA-frag-order bf16) ----
// WtF element (expert e, col, k): n16=col>>4, l15=col&15, ktl=(k>>6)&7,
// kk=(k>>5)&1, lhi=(k>>3)&3, j=k&7, lane=lhi*16+l15:
//   WtF[ ((((e*32+n16)*8 + ktl)*2 + kk)*64 + lane)*8 + j ]
__global__ void pack_xw_k(const f32x4* __restrict__ x, u16x4* __restrict__ xb,
                          const float* __restrict__ w, unsigned short* __restrict__ WtF) {
  __shared__ float tile[64][65];
  const int tid = threadIdx.x;
  if (blockIdx.x < 4096) {                      // pack x: 4096 blocks
    int gid = blockIdx.x * 256 + tid;
    f32x4 v = x[gid];
    u16x4 o;
    o[0] = f2bf(v[0]); o[1] = f2bf(v[1]); o[2] = f2bf(v[2]); o[3] = f2bf(v[3]);
    xb[gid] = o;
    return;
  }
  const int idx = blockIdx.x - 4096;            // pack w: 512 blocks
  const int kb = idx & 63, nb = idx >> 6;
  const int e = kb >> 3, ktl = kb & 7;
#pragma unroll
  for (int it = 0; it < 16; ++it) {
    int u = it * 256 + tid;
    int r = u >> 6, cc = u & 63;
    tile[r][cc] = w[(size_t)(e * 512 + ktl * 64 + r) * DOUT + nb * 64 + cc];
  }
  __syncthreads();
#pragma unroll
  for (int it = 0; it < 2; ++it) {
    int c = it * 256 + tid;
    int n16l = c >> 7, kk = (c >> 6) & 1, l = c & 63;
    int l15 = l & 15, lhi = l >> 4;
    int col_in = n16l * 16 + l15;
    int k_in   = kk * 32 + lhi * 8;
    int n16    = nb * 4 + n16l;
    u16x4 o0, o1;
    o0[0] = f2bf(tile[k_in + 0][col_in]); o0[1] = f2bf(tile[k_in + 1][col_in]);
    o0[2] = f2bf(tile[k_in + 2][col_in]); o0[3] = f2bf(tile[k_in + 3][col_in]);
    o1[0] = f2bf(tile[k_in + 4][col_in]); o1[1] = f2bf(tile[k_in + 5][col_in]);
    o1[2] = f2bf(tile[k_in + 6][col_in]); o1[3] = f2bf(tile[k_in + 7][col_in]);
    size_t base = ((((size_t)e * 32 + n16) * 8 + ktl) * 2 + kk) * 512 + l * 8;
    *(u16x4*)(WtF + base)     = o0;
    *(u16x4*)(WtF + base + 4) = o1;
  }
}

// ---- fused GEMM r13: 64x256 tile, FULL K=4096 (8 experts), NO partials ----
// grid 256 blocks (128 row-bands x 2 col-halves); 256 thr (4 waves, 1M x 4N).
// out f32 written directly, bias blend fused in epilogue -> reduce kernel GONE.
// B never touches LDS (frag-ordered 1KB coalesced reg loads; phase-locality
// keeps live expert slice ~1MB in L2). A: reg -> wt_e-scale -> LDS, r7's
// measured-0-conflict swizzle (row stride 128B, formulas verbatim); A staged
// 67MB total (2x less than r10). wt_e scalars via named-reg ping-pong with
// uniform branches (no reg-array indexing). LDS: 2x8KB staging; ep Cs[64][260].
__global__ __launch_bounds__(256) void gemm_k(
    const unsigned short* __restrict__ xb,   // [B_][DIN] bf16
    const unsigned short* __restrict__ WtF,  // frag-ordered weights
    const float* __restrict__ wt,            // [B_][NC] f32
    const float* __restrict__ bias,          // [NC][DOUT] f32
    float* __restrict__ out) {               // [B_][DOUT] f32
  extern __shared__ char smem[];
  const int tid  = threadIdx.x;
  const int lane = tid & 63, wn = tid >> 6;    // 4 waves across N
  const int l15 = lane & 15, lhi = lane >> 4;

  const int n0   = blockIdx.x;                 // 256 blocks
  const int by   = n0 >> 1, bn = n0 & 1;
  const int brow = by * 64, bcol = bn * 256;

  // ---- A staging: 64 rows x 64 k per tile; thread covers rows srow, srow+32 ----
  const int srow = tid >> 3, schunk = tid & 7;
  const int swz  = schunk ^ (srow & 7);        // (srow+32)&7 == srow&7
  const unsigned short* gA = xb + (size_t)(brow + srow) * DIN + schunk * 8;
  const int adst_off = srow * 128 + swz * 16;  // +4096 for row srow+32

  // ---- B frag bases (n16 = bn*16 + wn*4 + n) ----
  const unsigned short* bq0 = WtF + (size_t)(bn * 16 + wn * 4) * 8192 + lane * 8;
  const unsigned short* bq1 = bq0 + 8192;
  const unsigned short* bq2 = bq0 + 16384;
  const unsigned short* bq3 = bq0 + 24576;

  const float* gwA = wt + (size_t)(brow + srow) * NC;        // row srow
  const float* gwB = gwA + 32 * NC;                          // row srow+32

  f32x4 acc[4][4] = {};
  s16x8 areg0, areg1;
  s16x8 a[4], b0q[4], b1q[4];
  const int x7    = l15 & 7;
  const int pc0   = (lhi ^ x7) * 16;
  const int pc1   = ((4 + lhi) ^ x7) * 16;
  const int abase = l15 * 128;                 // a[m] at +m*2048

#define LOAD_B(BQ, et, ktl, kk) {                                            \
    const size_t o_ = (size_t)(et) * 262144 + ((ktl) * 2 + (kk)) * 512;      \
    BQ[0] = *(const s16x8*)(bq0 + o_);                                       \
    BQ[1] = *(const s16x8*)(bq1 + o_);                                       \
    BQ[2] = *(const s16x8*)(bq2 + o_);                                       \
    BQ[3] = *(const s16x8*)(bq3 + o_); }
#define LOAD_AREGS(kt) {                                                     \
    const unsigned short* s_ = gA + ((kt) & 7) * 64;                         \
    areg0 = *(const s16x8*)(s_);                                             \
    areg1 = *(const s16x8*)(s_ + (size_t)32 * DIN); }
#define SCALE_STORE(AR, S, P, slotb) {                                       \
    u32x4 v_;                                                                \
    v_[0] = cvtpk(bf2f((unsigned short)AR[0]) * (S),                         \
                  bf2f((unsigned short)AR[1]) * (S));                        \
    v_[1] = cvtpk(bf2f((unsigned short)AR[2]) * (S),                         \
                  bf2f((unsigned short)AR[3]) * (S));                        \
    v_[2] = cvtpk(bf2f((unsigned short)AR[4]) * (S),                         \
                  bf2f((unsigned short)AR[5]) * (S));                        \
    v_[3] = cvtpk(bf2f((unsigned short)AR[6]) * (S),                         \
                  bf2f((unsigned short)AR[7]) * (S));                        \
    *(u32x4*)(smem + (slotb) + adst_off + (P) * 4096) = v_; }
#define SCALE_WRITE2(SA, SB, slotb) {                                        \
    SCALE_STORE(areg0, SA, 0, slotb);                                        \
    SCALE_STORE(areg1, SB, 1, slotb); }
#define RD_A4(slotb, PC) {                                                   \
    const char* pa_ = smem + (slotb) + abase + (PC);                         \
    _Pragma("unroll") for (int m = 0; m < 4; ++m)                            \
      a[m] = *(const s16x8*)(pa_ + m * 2048); }
#define MFMA_HALF(BQ)                                                        \
    _Pragma("unroll") for (int m = 0; m < 4; ++m)                            \
      _Pragma("unroll") for (int n = 0; n < 4; ++n)                          \
        acc[m][n] = __builtin_amdgcn_mfma_f32_16x16x32_bf16(                 \
            a[m], BQ[n], acc[m][n], 0, 0, 0);

  // ---- prologue (expert 0) ----
  float wAc = gwA[0], wBc = gwB[0], wAn = 0.f, wBn = 0.f;
  LOAD_AREGS(0);
  SCALE_WRITE2(wAc, wBc, 0);
  LOAD_AREGS(1);
  LOAD_B(b0q, 0, 0, 0);
  __syncthreads();

#pragma unroll 2
  for (int t = 0; t < 64; ++t) {
    const int ct = (t & 1) * 8192, ot = 8192 - ct;
    RD_A4(ct, pc0);
    LOAD_B(b1q, t >> 3, t & 7, 1);
    MFMA_HALF(b0q);
    if ((t & 7) == 0 && t < 56) {              // prefetch next expert's wt (7 tiles early)
      wAn = gwA[(t + 8) >> 3]; wBn = gwB[(t + 8) >> 3];
    }
    if (t < 63) {
      const float sA = ((t & 7) == 7) ? wAn : wAc;   // expert of tile t+1
      const float sB = ((t & 7) == 7) ? wBn : wBc;
      SCALE_WRITE2(sA, sB, ot);
      if (t < 62) LOAD_AREGS(t + 2);
    }
    if ((t & 7) == 7) { wAc = wAn; wBc = wBn; }
    RD_A4(ct, pc1);
    MFMA_HALF(b1q);
    if (t < 63) LOAD_B(b0q, (t + 1) >> 3, (t + 1) & 7, 0);
    __syncthreads();
  }

  // ---- epilogue: repack to Cs[64][260] f32, fuse bias blend, write out ----
  float* Cs = (float*)smem;
#pragma unroll
  for (int m = 0; m < 4; ++m)
#pragma unroll
    for (int n = 0; n < 4; ++n) {
      const int row = m * 16 + lhi * 4;
      const int col = wn * 64 + n * 16 + l15;
      f32x4 v = acc[m][n];
#pragma unroll
      for (int j = 0; j < 4; ++j)
        Cs[(row + j) * 260 + col] = v[j];
    }
  __syncthreads();
#pragma unroll
  for (int it = 0; it < 16; ++it) {
    const int u   = it * 256 + tid;            // 4096 f32x4 chunks
    const int row = u >> 6, ch = u & 63;
    const int grow = brow + row, gcol = bcol + ch * 4;
    f32x4 v = *(const f32x4*)(Cs + row * 260 + ch * 4);
    const float* w8p = wt + (size_t)grow * NC;
#pragma unroll
    for (int c = 0; c < NC; ++c) {
      const float wc = w8p[c];
      f32x4 bv = *(const f32x4*)(bias + c * DOUT + gcol);
#pragma unroll
      for (int i = 0; i < 4; ++i) v[i] += wc * bv[i];
    }
    *(f32x4*)(out + (size_t)grow * DOUT + gcol) = v;
  }
#undef LOAD_B
#undef LOAD_AREGS
#undef SCALE_STORE
#undef SCALE_WRITE2
#undef RD_A4
#undef MFMA_HALF
}

// ---------------- fallback if ws too small ----------------
__global__ void bias_only_k(const float* __restrict__ wt,
                            const float* __restrict__ bias,
                            float* __restrict__ out) {
  int gid = blockIdx.x * 256 + threadIdx.x;
  int b = gid >> 7;
  int o4 = (gid & 127) << 2;
  float w8[8];
  *(f32x4*)w8       = *(const f32x4*)(wt + (size_t)b * NC);
  *(f32x4*)(w8 + 4) = *(const f32x4*)(wt + (size_t)b * NC + 4);
  f32x4 acc = {0.f, 0.f, 0.f, 0.f};
#pragma unroll
  for (int cc = 0; cc < NC; ++cc) {
    f32x4 bi = *(const f32x4*)(bias + cc * DOUT + o4);
#pragma unroll
    for (int i = 0; i < 4; ++i) acc[i] += w8[cc] * bi[i];
  }
  *(f32x4*)(out + (size_t)b * DOUT + o4) = acc;
}

extern "C" void kernel_launch(void* const* d_in, const int* in_sizes, int n_in,
                              void* d_out, int out_size, void* d_ws, size_t ws_size,
                              hipStream_t stream) {
  const float *x = nullptr, *wtc = nullptr, *w = nullptr, *bias = nullptr;
  for (int i = 0; i < n_in; ++i) {
    switch (in_sizes[i]) {
      case B_ * DIN:        x    = (const float*)d_in[i]; break;
      case B_ * NC:         wtc  = (const float*)d_in[i]; break;
      case NC * DIN * DOUT: w    = (const float*)d_in[i]; break;
      case NC * DOUT:       bias = (const float*)d_in[i]; break;
    }
  }
  float* out = (float*)d_out;

  const size_t XB_ELEMS = (size_t)B_ * DIN;
  const size_t WT_ELEMS = (size_t)NC * DIN * DOUT;
  const size_t need = (XB_ELEMS + WT_ELEMS) * sizeof(unsigned short);

  if (ws_size < need) {
    bias_only_k<<<(B_ * DOUT / 4) / 256, 256, 0, stream>>>(wtc, bias, out);
    return;
  }

  unsigned short* xb  = (unsigned short*)d_ws;
  unsigned short* WtF = xb + XB_ELEMS;

  const int GEMM_LDS = 64 * 260 * 4;   // 66560 B (K-loop uses first 16384)
  (void)hipFuncSetAttribute((const void*)gemm_k,
                            hipFuncAttributeMaxDynamicSharedMemorySize, GEMM_LDS);

  pack_xw_k<<<4096 + 512, 256, 0, stream>>>((const f32x4*)x, (u16x4*)xb, w, WtF);
  gemm_k<<<256, 256, GEMM_LDS, stream>>>(xb, WtF, wtc, bias, out);
}

// Round 14
// 78.663 us; speedup vs baseline: 1.2713x; 1.2713x over previous
//
#include <hip/hip_runtime.h>

#define B_   8192
#define DIN  512
#define DOUT 512
#define NC   8
#define KSPL 4

typedef float  f32x4 __attribute__((ext_vector_type(4)));
typedef short  s16x8 __attribute__((ext_vector_type(8)));
typedef unsigned short u16x4 __attribute__((ext_vector_type(4)));
typedef unsigned int   u32x4 __attribute__((ext_vector_type(4)));

__device__ __forceinline__ unsigned short f2bf(float f) {
  unsigned u = __builtin_bit_cast(unsigned, f);
  u += 0x7fffu + ((u >> 16) & 1u);          // RTNE
  return (unsigned short)(u >> 16);
}
__device__ __forceinline__ float bf2f(unsigned short h) {
  unsigned u = ((unsigned)h) << 16;
  return __builtin_bit_cast(float, u);
}
__device__ __forceinline__ unsigned cvtpk(float lo, float hi) {
  unsigned r;
  asm("v_cvt_pk_bf16_f32 %0, %1, %2" : "=v"(r) : "v"(lo), "v"(hi));
  return r;
}

// ---------- fused pack: x (f32->bf16) and w (f32 -> MFMA-frag-order bf16) ----
// WtF element (expert e, col, k): n16=col>>4, l15=col&15, ktl=(k>>6)&7,
// kk=(k>>5)&1, lhi=(k>>3)&3, j=k&7, lane=lhi*16+l15:
//   WtF[ ((((e*32+n16)*8 + ktl)*2 + kk)*64 + lane)*8 + j ]
__global__ void pack_xw_k(const f32x4* __restrict__ x, u16x4* __restrict__ xb,
                          const float* __restrict__ w, unsigned short* __restrict__ WtF) {
  __shared__ float tile[64][65];
  const int tid = threadIdx.x;
  if (blockIdx.x < 4096) {                      // pack x: 4096 blocks
    int gid = blockIdx.x * 256 + tid;
    f32x4 v = x[gid];
    u16x4 o;
    o[0] = f2bf(v[0]); o[1] = f2bf(v[1]); o[2] = f2bf(v[2]); o[3] = f2bf(v[3]);
    xb[gid] = o;
    return;
  }
  const int idx = blockIdx.x - 4096;            // pack w: 512 blocks
  const int kb = idx & 63, nb = idx >> 6;
  const int e = kb >> 3, ktl = kb & 7;
#pragma unroll
  for (int it = 0; it < 16; ++it) {
    int u = it * 256 + tid;
    int r = u >> 6, cc = u & 63;
    tile[r][cc] = w[(size_t)(e * 512 + ktl * 64 + r) * DOUT + nb * 64 + cc];
  }
  __syncthreads();
#pragma unroll
  for (int it = 0; it < 2; ++it) {
    int c = it * 256 + tid;
    int n16l = c >> 7, kk = (c >> 6) & 1, l = c & 63;
    int l15 = l & 15, lhi = l >> 4;
    int col_in = n16l * 16 + l15;
    int k_in   = kk * 32 + lhi * 8;
    int n16    = nb * 4 + n16l;
    u16x4 o0, o1;
    o0[0] = f2bf(tile[k_in + 0][col_in]); o0[1] = f2bf(tile[k_in + 1][col_in]);
    o0[2] = f2bf(tile[k_in + 2][col_in]); o0[3] = f2bf(tile[k_in + 3][col_in]);
    o1[0] = f2bf(tile[k_in + 4][col_in]); o1[1] = f2bf(tile[k_in + 5][col_in]);
    o1[2] = f2bf(tile[k_in + 6][col_in]); o1[3] = f2bf(tile[k_in + 7][col_in]);
    size_t base = ((((size_t)e * 32 + n16) * 8 + ktl) * 2 + kk) * 512 + l * 8;
    *(u16x4*)(WtF + base)     = o0;
    *(u16x4*)(WtF + base + 4) = o1;
  }
}

// ---- fused GEMM r14: 128x256 tile, 8 waves (2Mx4N), K=1024, 2 BLOCKS/CU ----
// Geometry chosen so ALL of these hold at once (the untried cell):
//  - staging volume = r10 parity (134MB; each 128-row band shared by 2 bn)
//  - acc = 64 VGPR/lane, lean body ~120 total <=128 -> 16 waves/CU resident
//  - LDS 67584B x 2 blocks = 135KB <= 160KB
// Single b[4] set (no dbuf): WAR forces read/MFMA interleave; cross-block TLP
// (m114) covers L2/B latency + barrier drains — that is this round's lever.
// B from frag-ordered WtF (1KB coalesced reg loads, per-XCD slice 512KB L2).
// A: reg -> wt-scale -> LDS with the measured-0-conflict XOR swizzle
// (phys chunk = logical ^ (row&7); read pc = (lhi^x7) — formulas verbatim).
__global__ __launch_bounds__(512, 2) void gemm_k(
    const unsigned short* __restrict__ xb,   // [B_][DIN] bf16
    const unsigned short* __restrict__ WtF,  // frag-ordered weights
    const float* __restrict__ wt,            // [B_][NC] f32
    unsigned short* __restrict__ part) {     // [KSPL][B_][DOUT] bf16
  extern __shared__ char smem[];
  const int tid  = threadIdx.x;
  const int lane = tid & 63, wid = tid >> 6;
  const int wm = wid >> 2, wn = wid & 3;       // 2 x 4 wave grid
  const int l15 = lane & 15, lhi = lane >> 4;

  const int n0   = blockIdx.x;                 // 512 blocks; xcd = n0&7 = (ks,bn)
  const int ks   = n0 & 3;                     // K-chunk: experts 2ks, 2ks+1
  const int bn   = (n0 >> 2) & 1;              // col half (256 cols)
  const int by   = n0 >> 3;                    // 0..63
  const int brow = by * 128, bcol = bn * 256;

  // ---- A staging: 128 rows x 64 k; thread -> row tid>>2, chunks sc, sc+4 ----
  const int srow = tid >> 2, sc = tid & 3;
  const int swz  = sc ^ (srow & 7);
  const unsigned short* gA = xb + (size_t)(brow + srow) * DIN + sc * 8;
  const int adst0 = srow * 128 + swz * 16;     // second chunk at adst0 ^ 64

  // ---- B frag bases (n16 = bn*16 + wn*4 + n), experts 2ks..2ks+1 ----
  const unsigned short* bq0 = WtF + (size_t)(ks * 2) * 262144
                                  + (size_t)(bn * 16 + wn * 4) * 8192 + lane * 8;
  const unsigned short* bq1 = bq0 + 8192;
  const unsigned short* bq2 = bq0 + 16384;
  const unsigned short* bq3 = bq0 + 24576;

  // routing weights: one row, two experts
  const float wtv0 = wt[(size_t)(brow + srow) * NC + ks * 2];
  const float wtv1 = wt[(size_t)(brow + srow) * NC + ks * 2 + 1];

  f32x4 acc[4][4] = {};
  s16x8 areg0, areg1;
  s16x8 a[4], b[4];
  const int x7    = l15 & 7;
  const int pc0   = (lhi ^ x7) * 16;           // phys chunk byte-offset, kk=0
  const int pc1   = ((4 + lhi) ^ x7) * 16;     // kk=1
  const int abase = (wm * 64 + l15) * 128;     // row stride 128B; a[m] +m*2048

#define LOAD_B(BQ, et, ktl, kk) {                                            \
    const size_t o_ = (size_t)(et) * 262144 + ((ktl) * 2 + (kk)) * 512;      \
    BQ[0] = *(const s16x8*)(bq0 + o_);                                       \
    BQ[1] = *(const s16x8*)(bq1 + o_);                                       \
    BQ[2] = *(const s16x8*)(bq2 + o_);                                       \
    BQ[3] = *(const s16x8*)(bq3 + o_); }
#define LOAD_AREGS(kt) {                                                     \
    const unsigned short* s_ = gA + ((kt) & 7) * 64;                         \
    areg0 = *(const s16x8*)(s_);                                             \
    areg1 = *(const s16x8*)(s_ + 32); }
#define SCALE_STORE(AR, S, DST) {                                            \
    u32x4 v_;                                                                \
    v_[0] = cvtpk(bf2f((unsigned short)AR[0]) * (S),                         \
                  bf2f((unsigned short)AR[1]) * (S));                        \
    v_[1] = cvtpk(bf2f((unsigned short)AR[2]) * (S),                         \
                  bf2f((unsigned short)AR[3]) * (S));                        \
    v_[2] = cvtpk(bf2f((unsigned short)AR[4]) * (S),                         \
                  bf2f((unsigned short)AR[5]) * (S));                        \
    v_[3] = cvtpk(bf2f((unsigned short)AR[6]) * (S),                         \
                  bf2f((unsigned short)AR[7]) * (S));                        \
    *(u32x4*)(smem + (DST)) = v_; }
#define SCALE_WRITE(e_, slotb) {                                             \
    const float s_ = (e_) ? wtv1 : wtv0;                                     \
    SCALE_STORE(areg0, s_, (slotb) + adst0);                                 \
    SCALE_STORE(areg1, s_, (slotb) + (adst0 ^ 64)); }
#define RD_A4(slotb, PC) {                                                   \
    const char* pa_ = smem + (slotb) + abase + (PC);                         \
    _Pragma("unroll") for (int m = 0; m < 4; ++m)                            \
      a[m] = *(const s16x8*)(pa_ + m * 2048); }
#define MFMA_HALF()                                                          \
    _Pragma("unroll") for (int m = 0; m < 4; ++m)                            \
      _Pragma("unroll") for (int n = 0; n < 4; ++n)                          \
        acc[m][n] = __builtin_amdgcn_mfma_f32_16x16x32_bf16(                 \
            a[m], b[n], acc[m][n], 0, 0, 0);

  // ---- prologue ----
  LOAD_AREGS(0);
  SCALE_WRITE(0, 0);
  LOAD_AREGS(1);
  __syncthreads();

  for (int t = 0; t < 16; ++t) {
    const int ct = (t & 1) * 16384, ot = 16384 - ct;
    const int et = t >> 3, ktl = t & 7;
    LOAD_B(b, et, ktl, 0);
    RD_A4(ct, pc0);
    MFMA_HALF();
    LOAD_B(b, et, ktl, 1);
    RD_A4(ct, pc1);
    if (t < 15) {
      SCALE_WRITE(((t + 1) >> 3), ot);
      if (t < 14) LOAD_AREGS(t + 2);
    }
    MFMA_HALF();
    __syncthreads();
  }

  // ---- epilogue: repack via Cs[128][264] bf16, full-line dwordx4 stores ----
  unsigned short* Cs = (unsigned short*)smem;
#pragma unroll
  for (int m = 0; m < 4; ++m)
#pragma unroll
    for (int n = 0; n < 4; ++n) {
      const int row = wm * 64 + m * 16 + lhi * 4;
      const int col = wn * 64 + n * 16 + l15;
      f32x4 v = acc[m][n];
#pragma unroll
      for (int j = 0; j < 4; ++j)
        Cs[(row + j) * 264 + col] = f2bf(v[j]);
    }
  __syncthreads();
  unsigned short* pc = part + (size_t)ks * (B_ * DOUT) + (size_t)brow * DOUT + bcol;
#pragma unroll
  for (int it = 0; it < 8; ++it) {
    const int u = it * 512 + tid;
    const int row = u >> 5, cu = (u & 31) * 8;
    f32x4 v = *(const f32x4*)(Cs + row * 264 + cu);
    *(f32x4*)(pc + (size_t)row * DOUT + cu) = v;
  }
#undef LOAD_B
#undef LOAD_AREGS
#undef SCALE_STORE
#undef SCALE_WRITE
#undef RD_A4
#undef MFMA_HALF
}

// -------- reduce: out = sum_s part_s + sum_c wt[b][c]*bias[c] --------
__global__ void reduce_k(const unsigned short* __restrict__ part,
                         const float* __restrict__ wt,
                         const float* __restrict__ bias,
                         float* __restrict__ out) {
  int gid = blockIdx.x * 256 + threadIdx.x;
  int b = gid >> 7;
  int o4 = (gid & 127) << 2;
  float w8[8];
  *(f32x4*)w8       = *(const f32x4*)(wt + (size_t)b * NC);
  *(f32x4*)(w8 + 4) = *(const f32x4*)(wt + (size_t)b * NC + 4);
  f32x4 acc = {0.f, 0.f, 0.f, 0.f};
  const size_t off = (size_t)b * DOUT + o4;
#pragma unroll
  for (int s = 0; s < KSPL; ++s) {
    u16x4 p = *(const u16x4*)(part + (size_t)s * (B_ * DOUT) + off);
#pragma unroll
    for (int i = 0; i < 4; ++i) acc[i] += bf2f(p[i]);
  }
#pragma unroll
  for (int cc = 0; cc < NC; ++cc) {
    f32x4 bi = *(const f32x4*)(bias + cc * DOUT + o4);
#pragma unroll
    for (int i = 0; i < 4; ++i) acc[i] += w8[cc] * bi[i];
  }
  *(f32x4*)(out + off) = acc;
}

// ---------------- fallback if ws too small ----------------
__global__ void bias_only_k(const float* __restrict__ wt,
                            const float* __restrict__ bias,
                            float* __restrict__ out) {
  int gid = blockIdx.x * 256 + threadIdx.x;
  int b = gid >> 7;
  int o4 = (gid & 127) << 2;
  float w8[8];
  *(f32x4*)w8       = *(const f32x4*)(wt + (size_t)b * NC);
  *(f32x4*)(w8 + 4) = *(const f32x4*)(wt + (size_t)b * NC + 4);
  f32x4 acc = {0.f, 0.f, 0.f, 0.f};
#pragma unroll
  for (int cc = 0; cc < NC; ++cc) {
    f32x4 bi = *(const f32x4*)(bias + cc * DOUT + o4);
#pragma unroll
    for (int i = 0; i < 4; ++i) acc[i] += w8[cc] * bi[i];
  }
  *(f32x4*)(out + (size_t)b * DOUT + o4) = acc;
}

extern "C" void kernel_launch(void* const* d_in, const int* in_sizes, int n_in,
                              void* d_out, int out_size, void* d_ws, size_t ws_size,
                              hipStream_t stream) {
  const float *x = nullptr, *wtc = nullptr, *w = nullptr, *bias = nullptr;
  for (int i = 0; i < n_in; ++i) {
    switch (in_sizes[i]) {
      case B_ * DIN:        x    = (const float*)d_in[i]; break;
      case B_ * NC:         wtc  = (const float*)d_in[i]; break;
      case NC * DIN * DOUT: w    = (const float*)d_in[i]; break;
      case NC * DOUT:       bias = (const float*)d_in[i]; break;
    }
  }
  float* out = (float*)d_out;

  const size_t XB_ELEMS   = (size_t)B_ * DIN;
  const size_t WT_ELEMS   = (size_t)NC * DIN * DOUT;
  const size_t PART_ELEMS = (size_t)KSPL * B_ * DOUT;
  const size_t need = (XB_ELEMS + WT_ELEMS + PART_ELEMS) * sizeof(unsigned short);

  if (ws_size < need) {
    bias_only_k<<<(B_ * DOUT / 4) / 256, 256, 0, stream>>>(wtc, bias, out);
    return;
  }

  unsigned short* xb   = (unsigned short*)d_ws;
  unsigned short* WtF  = xb + XB_ELEMS;
  unsigned short* part = WtF + WT_ELEMS;

  const int GEMM_LDS = 128 * 264 * 2;   // 67584 B -> 2 blocks/CU (135KB/160KB)
  (void)hipFuncSetAttribute((const void*)gemm_k,
                            hipFuncAttributeMaxDynamicSharedMemorySize, GEMM_LDS);

  pack_xw_k<<<4096 + 512, 256, 0, stream>>>((const f32x4*)x, (u16x4*)xb, w, WtF);
  gemm_k<<<512, 512, GEMM_LDS, stream>>>(xb, WtF, wtc, part);
  reduce_k<<<(B_ * DOUT / 4) / 256, 256, 0, stream>>>(part, wtc, bias, out);
}

// Round 15
// 62.369 us; speedup vs baseline: 1.6034x; 1.2612x over previous
//
#include <hip/hip_runtime.h>

#define B_   8192
#define DIN  512
#define DOUT 512
#define NC   8
#define NCD  (NC * DIN)
#define KSPL 4

typedef float  f32x4 __attribute__((ext_vector_type(4)));
typedef short  s16x8 __attribute__((ext_vector_type(8)));
typedef unsigned short u16x4 __attribute__((ext_vector_type(4)));
typedef unsigned int   u32x4 __attribute__((ext_vector_type(4)));

__device__ __forceinline__ unsigned short f2bf(float f) {
  unsigned u = __builtin_bit_cast(unsigned, f);
  u += 0x7fffu + ((u >> 16) & 1u);          // RTNE
  return (unsigned short)(u >> 16);
}
__device__ __forceinline__ float bf2f(unsigned short h) {
  unsigned u = ((unsigned)h) << 16;
  return __builtin_bit_cast(float, u);
}
__device__ __forceinline__ unsigned cvtpk(float lo, float hi) {
  unsigned r;
  asm("v_cvt_pk_bf16_f32 %0, %1, %2" : "=v"(r) : "v"(lo), "v"(hi));
  return r;
}

// ---------- fused pack: x (f32->bf16) and w (f32 -> MFMA-frag-order bf16) ----
// WtF element (expert e, col, k): n16=col>>4, l15=col&15, ktl=(k>>6)&7,
// kk=(k>>5)&1, lhi=(k>>3)&3, j=k&7, lane=lhi*16+l15:
//   WtF[ ((((e*32+n16)*8 + ktl)*2 + kk)*64 + lane)*8 + j ]
// -> a wave's b-frag load (fixed e,n16,ktl,kk) is 64 lanes x 16B CONTIGUOUS (1KB).
__global__ void pack_xw_k(const f32x4* __restrict__ x, u16x4* __restrict__ xb,
                          const float* __restrict__ w, unsigned short* __restrict__ WtF) {
  __shared__ float tile[64][65];
  const int tid = threadIdx.x;
  if (blockIdx.x < 4096) {                      // pack x: 4096 blocks
    int gid = blockIdx.x * 256 + tid;
    f32x4 v = x[gid];
    u16x4 o;
    o[0] = f2bf(v[0]); o[1] = f2bf(v[1]); o[2] = f2bf(v[2]); o[3] = f2bf(v[3]);
    xb[gid] = o;
    return;
  }
  const int idx = blockIdx.x - 4096;            // pack w: 512 blocks
  const int kb = idx & 63, nb = idx >> 6;       // kb: 64 k-tiles over NCD; nb: 8 col-tiles
  const int e = kb >> 3, ktl = kb & 7;
#pragma unroll
  for (int it = 0; it < 16; ++it) {
    int u = it * 256 + tid;
    int r = u >> 6, cc = u & 63;                // k-in-tile, col-in-tile
    tile[r][cc] = w[(size_t)(e * 512 + ktl * 64 + r) * DOUT + nb * 64 + cc];
  }
  __syncthreads();
#pragma unroll
  for (int it = 0; it < 2; ++it) {
    int c = it * 256 + tid;                     // 512 chunks of 8 elems
    int n16l = c >> 7, kk = (c >> 6) & 1, l = c & 63;
    int l15 = l & 15, lhi = l >> 4;
    int col_in = n16l * 16 + l15;
    int k_in   = kk * 32 + lhi * 8;
    int n16    = nb * 4 + n16l;
    u16x4 o0, o1;
    o0[0] = f2bf(tile[k_in + 0][col_in]); o0[1] = f2bf(tile[k_in + 1][col_in]);
    o0[2] = f2bf(tile[k_in + 2][col_in]); o0[3] = f2bf(tile[k_in + 3][col_in]);
    o1[0] = f2bf(tile[k_in + 4][col_in]); o1[1] = f2bf(tile[k_in + 5][col_in]);
    o1[2] = f2bf(tile[k_in + 6][col_in]); o1[3] = f2bf(tile[k_in + 7][col_in]);
    size_t base = ((((size_t)e * 32 + n16) * 8 + ktl) * 2 + kk) * 512 + l * 8;
    *(u16x4*)(WtF + base)     = o0;
    *(u16x4*)(WtF + base + 4) = o1;
  }
}

// ---- fused GEMM: part_s = (wt .* x) @ W', 256x256 tile, K=1024 (split-K 4) ----
// r10 (best measured): B NEVER touches LDS — b-frags are coalesced 1KB register
// loads from frag-ordered WtF (L1/L2-resident; 32KB/tile/block unique).
// LDS carries only A (2 slots x 32KB, r7's measured-0-conflict swizzle:
// phys chunk = logical ^ (row&7), on both ds_write and frag read).
// Per tile (ONE raw barrier); no manual vmcnt — compiler scoreboard.
__global__ __launch_bounds__(512, 2) void gemm_k(
    const unsigned short* __restrict__ xb,   // [B_][DIN] bf16
    const unsigned short* __restrict__ WtF,  // frag-ordered weights
    const float* __restrict__ wt,            // [B_][NC] f32
    unsigned short* __restrict__ part) {     // [KSPL][B_][DOUT] bf16
  extern __shared__ char smem[];
  const int tid  = threadIdx.x;
  const int lane = tid & 63, wid = tid >> 6;
  const int wm = wid >> 2, wn = wid & 3;       // 2 x 4 wave grid
  const int l15 = lane & 15, lhi = lane >> 4;

  const int n0   = blockIdx.x;                 // 256 blocks
  const int by   = n0 >> 3;                    // 0..31
  const int bx   = (n0 >> 2) & 1;              // 0..1
  const int ks   = n0 & 3;                     // K-chunk: experts 2ks, 2ks+1
  const int brow = by * 256, bcol = bx * 256;

  // ---- A staging (reg->scale->swizzled ds_write), r7 layout verbatim ----
  const int srow = tid >> 3, schunk = tid & 7;
  const int swz  = schunk ^ (srow & 7);
  const unsigned short* gA = xb + (size_t)(brow + srow) * DIN + schunk * 8;
  const int adst_off = srow * 128 + swz * 16;  // + slot + P*8192

  // ---- B frag-load bases (per wave n16 = bx*16 + wn*4 + n) ----
  const unsigned short* bn0 = WtF + (size_t)(ks * 2) * 262144
                                  + (size_t)(bx * 16 + wn * 4 + 0) * 8192 + lane * 8;
  const unsigned short* bn1 = bn0 + 8192;
  const unsigned short* bn2 = bn0 + 16384;
  const unsigned short* bn3 = bn0 + 24576;

  // routing weights for this block's rows x 2 experts (held in VGPRs)
  const float* wtp = wt + (size_t)(brow + srow) * NC + ks * 2;
  const float wtv0_0 = wtp[0],            wtv1_0 = wtp[1];
  const float wtv0_1 = wtp[64 * NC],      wtv1_1 = wtp[64 * NC + 1];
  const float wtv0_2 = wtp[128 * NC],     wtv1_2 = wtp[128 * NC + 1];
  const float wtv0_3 = wtp[192 * NC],     wtv1_3 = wtp[192 * NC + 1];

  f32x4 acc[8][4] = {};
  s16x8 areg0, areg1, areg2, areg3;
  s16x8 a[8], b0q[4], b1q[4];
  const int x7    = l15 & 7;
  const int pc0   = (lhi ^ x7) * 16;           // phys chunk byte-offset, kk=0
  const int pc1   = ((4 + lhi) ^ x7) * 16;     // kk=1
  const int abase = (wm * 128 + l15) * 128;    // row stride 128B, a[m] +m*2048

#define LOAD_B(BQ, et, ktl, kk) {                                            \
    const size_t o_ = (size_t)(et) * 262144 + ((ktl) * 2 + (kk)) * 512;      \
    BQ[0] = *(const s16x8*)(bn0 + o_);                                       \
    BQ[1] = *(const s16x8*)(bn1 + o_);                                       \
    BQ[2] = *(const s16x8*)(bn2 + o_);                                       \
    BQ[3] = *(const s16x8*)(bn3 + o_); }
#define LOAD_AREGS(kt) {                                                     \
    const unsigned short* s_ = gA + ((kt) & 7) * 64;                         \
    areg0 = *(const s16x8*)(s_);                                             \
    areg1 = *(const s16x8*)(s_ + (size_t) 64 * DIN);                         \
    areg2 = *(const s16x8*)(s_ + (size_t)128 * DIN);                         \
    areg3 = *(const s16x8*)(s_ + (size_t)192 * DIN); }
#define SCALE_STORE(AR, S, P, slotb) {                                       \
    u32x4 v_;                                                                \
    v_[0] = cvtpk(bf2f((unsigned short)AR[0]) * (S),                         \
                  bf2f((unsigned short)AR[1]) * (S));                        \
    v_[1] = cvtpk(bf2f((unsigned short)AR[2]) * (S),                         \
                  bf2f((unsigned short)AR[3]) * (S));                        \
    v_[2] = cvtpk(bf2f((unsigned short)AR[4]) * (S),                         \
                  bf2f((unsigned short)AR[5]) * (S));                        \
    v_[3] = cvtpk(bf2f((unsigned short)AR[6]) * (S),                         \
                  bf2f((unsigned short)AR[7]) * (S));                        \
    *(u32x4*)(smem + (slotb) + adst_off + (P) * 8192) = v_; }
#define SCALE_WRITE_ALL(e_, slotb) {                                         \
    SCALE_STORE(areg0, (e_) ? wtv1_0 : wtv0_0, 0, slotb);                    \
    SCALE_STORE(areg1, (e_) ? wtv1_1 : wtv0_1, 1, slotb);                    \
    SCALE_STORE(areg2, (e_) ? wtv1_2 : wtv0_2, 2, slotb);                    \
    SCALE_STORE(areg3, (e_) ? wtv1_3 : wtv0_3, 3, slotb); }
#define RD_A8(slotb, PC) {                                                   \
    const char* pa_ = smem + (slotb) + abase + (PC);                         \
    _Pragma("unroll") for (int m = 0; m < 8; ++m)                            \
      a[m] = *(const s16x8*)(pa_ + m * 2048); }
#define MFMA_HALF(BQ)                                                        \
    _Pragma("unroll") for (int m = 0; m < 8; ++m)                            \
      _Pragma("unroll") for (int n = 0; n < 4; ++n)                          \
        acc[m][n] = __builtin_amdgcn_mfma_f32_16x16x32_bf16(                 \
            a[m], BQ[n], acc[m][n], 0, 0, 0);
#define BAR()   __builtin_amdgcn_s_barrier()
#define PRIO1() __builtin_amdgcn_s_setprio(1)
#define PRIO0() __builtin_amdgcn_s_setprio(0)
#define SBAR0() __builtin_amdgcn_sched_barrier(0)
#define WAITL() asm volatile("s_waitcnt lgkmcnt(0)" ::: "memory")

  // ---- prologue: A(0) scale->slot0, A(1) in flight, b0q(0) in flight ----
  LOAD_AREGS(0);
  SCALE_WRITE_ALL(0, 0);          // compiler waits A(0) regs
  LOAD_AREGS(1);
  LOAD_B(b0q, 0, 0, 0);
  WAITL();                        // ds_writes drained
  BAR();                          // raw: AREGS(1)+b0q legally in flight

  for (int t = 0; t < 16; ++t) {
    const int ct = (t & 1) * 32768, ot = 32768 - ct;
    const int ktl = t & 7, et = t >> 3;
    // ---- kk0 ----
    RD_A8(ct, pc0);
    LOAD_B(b1q, et, ktl, 1);
    WAITL(); SBAR0();
    PRIO1(); MFMA_HALF(b0q); PRIO0();
    // ---- kk1 ----
    RD_A8(ct, pc1);
    if (t < 15) {
      SCALE_WRITE_ALL(((t + 1) >> 3), ot);   // compiler waits A(t+1) regs
      if (t < 14) LOAD_AREGS(t + 2);
    }
    WAITL(); SBAR0();
    PRIO1(); MFMA_HALF(b1q); PRIO0();
    if (t < 15) LOAD_B(b0q, ((t + 1) >> 3), ((t + 1) & 7), 0);
    BAR();                        // writes to ot drained by WAITL above
  }

  // ---- epilogue: repack via LDS, then full-line dwordx4 stores ----
  __syncthreads();
  unsigned short* Cs = (unsigned short*)smem;   // [256][264] bf16
#pragma unroll
  for (int m = 0; m < 8; ++m)
#pragma unroll
    for (int n = 0; n < 4; ++n) {
      const int row = wm * 128 + m * 16 + lhi * 4;
      const int col = wn * 64 + n * 16 + l15;
      f32x4 v = acc[m][n];
#pragma unroll
      for (int j = 0; j < 4; ++j)
        Cs[(row + j) * 264 + col] = f2bf(v[j]);
    }
  __syncthreads();
  unsigned short* pc = part + (size_t)ks * (B_ * DOUT) + (size_t)brow * DOUT + bcol;
#pragma unroll
  for (int it = 0; it < 16; ++it) {
    const int u = it * 512 + tid;
    const int row = u >> 5, cu = (u & 31) * 8;
    f32x4 v = *(const f32x4*)(Cs + row * 264 + cu);
    *(f32x4*)(pc + (size_t)row * DOUT + cu) = v;
  }
#undef LOAD_B
#undef LOAD_AREGS
#undef SCALE_STORE
#undef SCALE_WRITE_ALL
#undef RD_A8
#undef MFMA_HALF
#undef BAR
#undef PRIO1
#undef PRIO0
#undef SBAR0
#undef WAITL
}

// -------- reduce: out = sum_s part_s + sum_c wt[b][c]*bias[c] --------
__global__ void reduce_k(const unsigned short* __restrict__ part,
                         const float* __restrict__ wt,
                         const float* __restrict__ bias,
                         float* __restrict__ out) {
  int gid = blockIdx.x * 256 + threadIdx.x;
  int b = gid >> 7;
  int o4 = (gid & 127) << 2;
  float w8[8];
  *(f32x4*)w8       = *(const f32x4*)(wt + (size_t)b * NC);
  *(f32x4*)(w8 + 4) = *(const f32x4*)(wt + (size_t)b * NC + 4);
  f32x4 acc = {0.f, 0.f, 0.f, 0.f};
  const size_t off = (size_t)b * DOUT + o4;
#pragma unroll
  for (int s = 0; s < KSPL; ++s) {
    u16x4 p = *(const u16x4*)(part + (size_t)s * (B_ * DOUT) + off);
#pragma unroll
    for (int i = 0; i < 4; ++i) acc[i] += bf2f(p[i]);
  }
#pragma unroll
  for (int cc = 0; cc < NC; ++cc) {
    f32x4 bi = *(const f32x4*)(bias + cc * DOUT + o4);
#pragma unroll
    for (int i = 0; i < 4; ++i) acc[i] += w8[cc] * bi[i];
  }
  *(f32x4*)(out + off) = acc;
}

// ---------------- fallback if ws too small ----------------
__global__ void bias_only_k(const float* __restrict__ wt,
                            const float* __restrict__ bias,
                            float* __restrict__ out) {
  int gid = blockIdx.x * 256 + threadIdx.x;
  int b = gid >> 7;
  int o4 = (gid & 127) << 2;
  float w8[8];
  *(f32x4*)w8       = *(const f32x4*)(wt + (size_t)b * NC);
  *(f32x4*)(w8 + 4) = *(const f32x4*)(wt + (size_t)b * NC + 4);
  f32x4 acc = {0.f, 0.f, 0.f, 0.f};
#pragma unroll
  for (int cc = 0; cc < NC; ++cc) {
    f32x4 bi = *(const f32x4*)(bias + cc * DOUT + o4);
#pragma unroll
    for (int i = 0; i < 4; ++i) acc[i] += w8[cc] * bi[i];
  }
  *(f32x4*)(out + (size_t)b * DOUT + o4) = acc;
}

extern "C" void kernel_launch(void* const* d_in, const int* in_sizes, int n_in,
                              void* d_out, int out_size, void* d_ws, size_t ws_size,
                              hipStream_t stream) {
  const float *x = nullptr, *wtc = nullptr, *w = nullptr, *bias = nullptr;
  for (int i = 0; i < n_in; ++i) {
    switch (in_sizes[i]) {
      case B_ * DIN:        x    = (const float*)d_in[i]; break;
      case B_ * NC:         wtc  = (const float*)d_in[i]; break;
      case NC * DIN * DOUT: w    = (const float*)d_in[i]; break;
      case NC * DOUT:       bias = (const float*)d_in[i]; break;
    }
  }
  float* out = (float*)d_out;

  const size_t XB_ELEMS   = (size_t)B_ * DIN;
  const size_t WT_ELEMS   = (size_t)NC * DIN * DOUT;
  const size_t PART_ELEMS = (size_t)KSPL * B_ * DOUT;
  const size_t need = (XB_ELEMS + WT_ELEMS + PART_ELEMS) * sizeof(unsigned short);

  if (ws_size < need) {
    bias_only_k<<<(B_ * DOUT / 4) / 256, 256, 0, stream>>>(wtc, bias, out);
    return;
  }

  unsigned short* xb   = (unsigned short*)d_ws;
  unsigned short* WtF  = xb + XB_ELEMS;
  unsigned short* part = WtF + WT_ELEMS;

  const int GEMM_LDS = 256 * 264 * 2;   // 135168 B (K-loop uses first 65536)
  (void)hipFuncSetAttribute((const void*)gemm_k,
                            hipFuncAttributeMaxDynamicSharedMemorySize, GEMM_LDS);

  pack_xw_k<<<4096 + 512, 256, 0, stream>>>((const f32x4*)x, (u16x4*)xb, w, WtF);
  gemm_k<<<256, 512, GEMM_LDS, stream>>>(xb, WtF, wtc, part);
  reduce_k<<<(B_ * DOUT / 4) / 256, 256, 0, stream>>>(part, wtc, bias, out);
}